// Round 5
// baseline (2192.244 us; speedup 1.0000x reference)
//
#include <hip/hip_runtime.h>
#include <math.h>

constexpr int VOX = 128 * 128 * 128;     // 2,097,152
constexpr int NPIX = 16 * 128 * 128;     // 262,144
constexpr int NS = 16;
constexpr float RES_RATIO = 1.5f;
constexpr int CSTR = 128;
// a_kernel LDS tile dims (provable bounds: x,y extent <= 18.1, z <= 8.1)
constexpr int TNX = 19, TNY = 19, TNZ = 10;
// at_scatter z-slots per column: window length 2*lim/r22 <= 4.55 -> <=5 ints
constexpr int ZSL = 5;

// Per-slice constant block (floats, stride 128):
//  [0..11]  T row-major  [12..14] tc=t+63.5  [15..17] col L1 norms
//  [18..20] row L1 norms [21..22] z slab     [24+3k..] rotated PSF offsets
//  [105..109] at_scatter hoists: lim, 1/r22, -r20*tc2, -r21*tc2, -r22*tc2
// Globals at cst+NS*CSTR: separable psf fx[3],fy[3],fz[3] (1/c^2 in fz)

__global__ __launch_bounds__(512) void prep_kernel(
    const float* __restrict__ theta, const float* __restrict__ psf,
    float* __restrict__ cst, int* __restrict__ zb)
{
    int tid = threadIdx.x;
    int n = tid >> 5, j = tid & 31;
    if (n < NS) {
        const float* T = theta + n * 12;
        float* C = cst + n * CSTR;
        if (j < 12) C[j] = T[j];
        if (j == 12) {
            float r00=T[0], r01=T[1], r02=T[2],  t0=T[3];
            float r10=T[4], r11=T[5], r12=T[6],  t1=T[7];
            float r20=T[8], r21=T[9], r22=T[10], t2=T[11];
            float tc0 = t0 + 63.5f, tc1 = t1 + 63.5f, tc2 = t2 + 63.5f;
            C[12]=tc0; C[13]=tc1; C[14]=tc2;
            float C2 = fabsf(r02)+fabsf(r12)+fabsf(r22);
            C[15] = fabsf(r00)+fabsf(r10)+fabsf(r20);
            C[16] = fabsf(r01)+fabsf(r11)+fabsf(r21);
            C[17] = C2;
            C[18] = fabsf(r00)+fabsf(r01)+fabsf(r02);
            C[19] = fabsf(r10)+fabsf(r11)+fabsf(r12);
            C[20] = fabsf(r20)+fabsf(r21)+fabsf(r22);
            // conservative slab (covers at_scatter's widened per-column ranges)
            float mx = fmaxf(tc0, 127.0f - tc0);
            float my = fmaxf(tc1, 127.0f - tc1);
            float marg = 1.05f + C2 + fabsf(r02)*mx + fabsf(r12)*my;
            float inv = 1.0f / fabsf(r22);
            C[21] = tc2 - marg * inv;
            C[22] = tc2 + marg * inv;
            // at_scatter per-thread hoists (bitwise-equal expressions)
            C[105] = 1.0f + C2 + 0.01f;      // lim
            C[106] = 1.0f / r22;             // inv22 (r22 > 0 always)
            C[107] = -(r20 * tc2);           // ax const
            C[108] = -(r21 * tc2);           // ay const
            C[109] = -(r22 * tc2);           // az const
        }
        if (j < 27) {
            float ox = (float)(j % 3) - 1.0f;
            float oy = (float)((j / 3) % 3) - 1.0f;
            float oz = (float)(j / 9) - 1.0f;
            C[24 + 3*j + 0] = T[0]*ox + T[1]*oy + T[2]*oz;
            C[24 + 3*j + 1] = T[4]*ox + T[5]*oy + T[6]*oz;
            C[24 + 3*j + 2] = T[8]*ox + T[9]*oy + T[10]*oz;
        }
    }
    __syncthreads();
    if (tid == 0) {
        float zmin = 1e30f, zmax = -1e30f;
        for (int s = 0; s < NS; ++s) {
            zmin = fminf(zmin, cst[s * CSTR + 21]);
            zmax = fmaxf(zmax, cst[s * CSTR + 22]);
        }
        zb[0] = max(0, (int)floorf(zmin));
        zb[1] = min(127, (int)ceilf(zmax));
        float* G = cst + NS * CSTR;
        float c = psf[13];
        float ic2 = 1.0f / (c * c);
        G[0]=psf[12]; G[1]=psf[13]; G[2]=psf[14];
        G[3]=psf[10]; G[4]=psf[13]; G[5]=psf[16];
        G[6]=psf[4]*ic2; G[7]=psf[13]*ic2; G[8]=psf[22]*ic2;
    }
}

// ---------------------------------------------------------------------------
// block_reduce_spread: 64 spread slots (stride 32 doubles). Contains
// __syncthreads(): only block-uniform early returns may precede it.
// ---------------------------------------------------------------------------
__device__ __forceinline__ void block_reduce_spread(double s, double* slots)
{
    #pragma unroll
    for (int off = 32; off > 0; off >>= 1)
        s += __shfl_down(s, off, 64);
    __shared__ double ls[4];
    if ((threadIdx.x & 63) == 0) ls[threadIdx.x >> 6] = s;
    __syncthreads();
    if (threadIdx.x == 0)
        atomicAdd(&slots[(blockIdx.x & 63) * 32], ls[0] + ls[1] + ls[2] + ls[3]);
}

// ---------------------------------------------------------------------------
// A: PSF-weighted trilinear gather, LDS-tiled (64-thread blocks, 8x8 patch).
// If subsrc != null: out = subsrc - A(vol). Block 0 zeroes slot arrays
// (including the fused-kernel sync slots aliased into paps[1..7]).
// Staging loop uses an incremental (gx,gy,gz) walk (step 64 = +7 x, +3 y,
// carries) instead of per-iteration div/mod by 19 — verified equivalent.
// ---------------------------------------------------------------------------
__global__ __launch_bounds__(64, 4) void a_kernel(
    const float* __restrict__ cst, const float* __restrict__ vol,
    const float* __restrict__ psf, float* __restrict__ out,
    const float* __restrict__ subsrc,
    double* __restrict__ z1, double* __restrict__ z2, double* __restrict__ z3)
{
    int tid = threadIdx.x;
    if (blockIdx.x == 0) {
        for (int i = tid; i < 2048; i += 64) {
            if (z1) z1[i] = 0.0;
            if (z2) z2[i] = 0.0;
            if (z3) z3[i] = 0.0;
        }
    }

    int b = blockIdx.x;              // 4096 blocks: n = b>>8, patch = b&255
    int n = b >> 8;
    int pb = b & 255;
    int w0 = (pb & 15) << 3, h0 = (pb >> 4) << 3;
    int w = w0 + (tid & 7), h = h0 + (tid >> 3);
    int oidx = (n << 14) + (h << 7) + w;
    float base = subsrc ? subsrc[oidx] : 0.0f;
    float sgn = subsrc ? -1.0f : 1.0f;

    const float* C = cst + n * CSTR;
    float r00=C[0], r01=C[1];
    float r10=C[4], r11=C[5];
    float r20=C[8], r21=C[9];

    float uc = (w0 + 3.5f - 63.5f) * RES_RATIO;
    float vc = (h0 + 3.5f - 63.5f) * RES_RATIO;
    const float du = 5.25f, dv = 5.25f;
    float cx = r00*uc + r01*vc + C[12];
    float cy = r10*uc + r11*vc + C[13];
    float cz = r20*uc + r21*vc + C[14];
    float hx = fabsf(r00)*du + fabsf(r01)*dv + C[18];
    float hy = fabsf(r10)*du + fabsf(r11)*dv + C[19];
    float hz = fabsf(r20)*du + fabsf(r21)*dv + C[20];
    int tx0 = (int)floorf(cx - hx);
    int ty0 = (int)floorf(cy - hy);
    int tz0 = (int)floorf(cz - hz);

    if (tx0 >= 128 || tx0 + TNX <= 0 || ty0 >= 128 || ty0 + TNY <= 0 ||
        tz0 >= 128 || tz0 + TNZ <= 0) {
        out[oidx] = base;
        return;
    }

    __shared__ float tile[TNZ * TNY * TNX];
    {
        int gx = tx0 + tid % TNX;
        int gy = ty0 + tid / TNX;
        int gz = tz0;
        const int gxe = tx0 + TNX, gye = ty0 + TNY;
        for (int i = tid; i < TNZ * TNY * TNX; i += 64) {
            bool ok = ((unsigned)gx < 128u) & ((unsigned)gy < 128u) & ((unsigned)gz < 128u);
            int off = ok ? ((gz << 14) + (gy << 7) + gx) : 0;
            float v = vol[off];
            tile[i] = ok ? v : 0.0f;
            gx += 7; gy += 3;                  // step 64 = 3*19 + 7
            if (gx >= gxe) { gx -= TNX; gy += 1; }
            if (gy >= gye) { gy -= TNY; gz += 1; }
        }
    }
    __syncthreads();

    float u = (w - 63.5f) * RES_RATIO;
    float v = (h - 63.5f) * RES_RATIO;
    float px = fmaf(r00, u, fmaf(r01, v, C[12])) - (float)tx0;
    float py = fmaf(r10, u, fmaf(r11, v, C[13])) - (float)ty0;
    float pz = fmaf(r20, u, fmaf(r21, v, C[14])) - (float)tz0;

    const float* O = C + 24;
    float acc = 0.0f;
    for (int k = 0; k < 27; ++k) {
        float sx = px + O[3*k+0];
        float sy = py + O[3*k+1];
        float sz = pz + O[3*k+2];
        int x0 = (int)sx, y0 = (int)sy, z0 = (int)sz;
        float fx = sx - (float)x0, fy = sy - (float)y0, fz = sz - (float)z0;
        const float* tp = tile + (z0 * TNY + y0) * TNX + x0;
        float c000 = tp[0],             c001 = tp[1];
        float c010 = tp[TNX],           c011 = tp[TNX+1];
        float c100 = tp[TNY*TNX],       c101 = tp[TNY*TNX+1];
        float c110 = tp[TNY*TNX+TNX],   c111 = tp[TNY*TNX+TNX+1];
        float c00 = fmaf(fx, c001 - c000, c000);
        float c01 = fmaf(fx, c011 - c010, c010);
        float c10 = fmaf(fx, c101 - c100, c100);
        float c11 = fmaf(fx, c111 - c110, c110);
        float c0  = fmaf(fy, c01 - c00, c00);
        float c1  = fmaf(fy, c11 - c10, c10);
        acc = fmaf(psf[k], fmaf(fz, c1 - c0, c0), acc);
    }
    out[oidx] = fmaf(sgn, acc, base);
}

// ---------------------------------------------------------------------------
// At, z-split scatter (unchanged arithmetic from R4; contributions bitwise-
// identical). PSF symmetry (pfx0==pfx2, pfy0==pfy2 bitwise: Gaussian, (+-1)^2
// computed identically on host) lets fx/fy selects collapse to 1 cndmask —
// selection among bitwise-equal values, exact.
// ~1.2M atomicAdds total; outvol must be pre-zeroed. No barriers.
// ---------------------------------------------------------------------------
#define ATS_CL(B_) fmaxf(1.0f - fabsf(B_), 0.0f)
#define ATS_PT(cAi, cBi, cCi, Xai, Yai, Zai, SEL, fyj, mvj, ACC) { \
    float sf_  = SEL(cAi, cBi, cCi); \
    float svf_ = sf_ * fyj; \
    float Bx_ = fmaf(r01, mvj, Xai); \
    float By_ = fmaf(r11, mvj, Yai); \
    float Bz_ = fmaf(r21, mvj, Zai); \
    float w0_ = ATS_CL(Bx_ - r02) * ATS_CL(By_ - r12) * ATS_CL(Bz_ - r22); \
    float w1_ = ATS_CL(Bx_) * ATS_CL(By_) * ATS_CL(Bz_); \
    float w2_ = ATS_CL(Bx_ + r02) * ATS_CL(By_ + r12) * ATS_CL(Bz_ + r22); \
    float t_  = fmaf(w0_, pfz0, fmaf(w1_, pfz1, w2_ * pfz2)); \
    ACC = fmaf(t_, svf_, ACC); }
#define ATS_ROW(SEL, fyj, mvj) \
    ATS_PT(cA0,cB0,cC0, Xa0,Ya0,Za0, SEL, fyj, mvj, acc0) \
    ATS_PT(cA1,cB1,cC1, Xa1,Ya1,Za1, SEL, fyj, mvj, acc1) \
    ATS_PT(cA2,cB2,cC2, Xa2,Ya2,Za2, SEL, fyj, mvj, acc0) \
    ATS_PT(cA3,cB3,cC3, Xa3,Ya3,Za3, SEL, fyj, mvj, acc1) \
    ATS_PT(cA4,cB4,cC4, Xa4,Ya4,Za4, SEL, fyj, mvj, acc0)
#define SEL_J0(a,b,c) (mj1 ? (b) : (a))
#define SEL_J1(a,b,c) (mj1 ? (a) : (b))
#define SEL_J2(a,b,c) (mj1 ? (b) : (mj2 ? (c) : (a)))
#define SEL_J3(a,b,c) (mj1 ? (c) : (b))
#define SEL_J4(a,b,c) (mj1 ? (b) : (c))

__global__ __launch_bounds__(256, 4) void at_scatter_kernel(
    const float* __restrict__ cst, const float* __restrict__ sl,
    float* __restrict__ outvol)
{
    int id = blockIdx.x * 256 + threadIdx.x;    // exact grid: NPIX*ZSL threads
    int x = id & 127, y = (id >> 7) & 127;
    int n = (id >> 14) & 15, zi = id >> 18;     // n, zi block-uniform
    const float* C = cst + n * CSTR;
    float r00=C[0], r01=C[1], r02=C[2];
    float r10=C[4], r11=C[5], r12=C[6];
    float r20=C[8], r21=C[9], r22=C[10];
    float tc2 = C[14];
    float C0=C[15], C1=C[16];

    float gx = (float)x - C[12];
    float gy = (float)y - C[13];

    // gpz(z) = az + r22*z ; active: |gpz| < lim. r22 > 0 always.
    float az = r02*gx + r12*gy + C[109];
    float lim = C[105];
    float inv22 = C[106];
    int z0 = (int)ceilf((-lim - az) * inv22);
    int z1v = (int)floorf(( lim - az) * inv22);
    z0 = max(z0, 0); z1v = min(z1v, 127);
    int z = z0 + zi;
    if (z > z1v) return;                        // no barriers: safe

    float ax = r00*gx + r10*gy + C[107];        // gpx = ax + r20*z
    float ay = r01*gx + r11*gy + C[108];        // gpy = ay + r21*z

    float fzv = (float)z;
    float gpx = fmaf(r20, fzv, ax);
    float gpy = fmaf(r21, fzv, ay);
    float gz  = fzv - tc2;
    int m2 = (int)floorf(2.0f*(gpx + 95.25f - C0)) + 601;
    int n2 = (int)floorf(2.0f*(gpy + 95.25f - C1)) + 601;
    int wb0 = m2 / 3;                           // biased by 200 (per-z anchor)
    int hb0 = n2 / 3;
    int ki0 = m2 - wb0 * 3;
    int kj0 = n2 - hb0 * 3;

    // 3x3 sval register block, OOB-masked (per-z anchor => ci,rj in 0..2)
    const float* slice_n = sl + (n << 14);
    float s[3][3];
    #pragma unroll
    for (int aa = 0; aa < 3; ++aa) {
        int hv = hb0 - 200 + aa;
        bool hok = ((unsigned)hv < 128u);
        #pragma unroll
        for (int cc = 0; cc < 3; ++cc) {
            int wv = wb0 - 200 + cc;
            bool ok = hok & ((unsigned)wv < 128u);
            int off = ok ? ((hv << 7) + wv) : 0;
            float vs = slice_n[off];
            s[aa][cc] = ok ? vs : 0.0f;
        }
    }

    const float* G = cst + NS * CSTR;
    float pfx0=G[0], pfx1=G[1];
    float pfy0=G[3], pfy1=G[4];
    float pfz0=G[6], pfz1=G[7], pfz2=G[8];

    int yx = (y << 7) + x;

    bool mi0 = (ki0 == 0), mi1 = (ki0 == 1), mi2 = (ki0 == 2);
    bool mj0 = (kj0 == 0), mj1 = (kj0 == 1), mj2 = (kj0 == 2);

    // fx values (period 3; pfx0==pfx2 bitwise -> single selects)
    float fxA = mi0 ? pfx1 : pfx0;
    float fxB = mi2 ? pfx1 : pfx0;
    float fxC = mi1 ? pfx1 : pfx0;

    float fyA = mj0 ? pfy1 : pfy0;
    float fyB = mj2 ? pfy1 : pfy0;
    float fyC = mj1 ? pfy1 : pfy0;

    // Column-selected s-values per i (R2 tables), premultiplied by fx — all
    // named scalars, pinned below (kept from R4; neutral but harmless).
    float cA0 = (mi1 ? s[0][1] : s[0][0]) * fxA;
    float cB0 = (mi1 ? s[1][1] : s[1][0]) * fxA;
    float cC0 = (mi1 ? s[2][1] : s[2][0]) * fxA;
    float cA1 = (mi1 ? s[0][0] : s[0][1]) * fxB;
    float cB1 = (mi1 ? s[1][0] : s[1][1]) * fxB;
    float cC1 = (mi1 ? s[2][0] : s[2][1]) * fxB;
    float cA2 = (mi1 ? s[0][1] : (mi2 ? s[0][2] : s[0][0])) * fxC;
    float cB2 = (mi1 ? s[1][1] : (mi2 ? s[1][2] : s[1][0])) * fxC;
    float cC2 = (mi1 ? s[2][1] : (mi2 ? s[2][2] : s[2][0])) * fxC;
    float cA3 = (mi1 ? s[0][2] : s[0][1]) * fxA;
    float cB3 = (mi1 ? s[1][2] : s[1][1]) * fxA;
    float cC3 = (mi1 ? s[2][2] : s[2][1]) * fxA;
    float cA4 = (mi1 ? s[0][1] : s[0][2]) * fxB;
    float cB4 = (mi1 ? s[1][1] : s[1][2]) * fxB;
    float cC4 = (mi1 ? s[2][1] : s[2][2]) * fxB;

    float mu0_ = 0.5f * (float)(m2 - 600) - 95.25f;
    float mu1_ = 0.5f * (float)(m2 - 599) - 95.25f;
    float mu2_ = 0.5f * (float)(m2 - 598) - 95.25f;
    float mu3_ = 0.5f * (float)(m2 - 597) - 95.25f;
    float mu4_ = 0.5f * (float)(m2 - 596) - 95.25f;
    float Xa0 = fmaf(r00, mu0_, -gx), Ya0 = fmaf(r10, mu0_, -gy), Za0 = fmaf(r20, mu0_, -gz);
    float Xa1 = fmaf(r00, mu1_, -gx), Ya1 = fmaf(r10, mu1_, -gy), Za1 = fmaf(r20, mu1_, -gz);
    float Xa2 = fmaf(r00, mu2_, -gx), Ya2 = fmaf(r10, mu2_, -gy), Za2 = fmaf(r20, mu2_, -gz);
    float Xa3 = fmaf(r00, mu3_, -gx), Ya3 = fmaf(r10, mu3_, -gy), Za3 = fmaf(r20, mu3_, -gz);
    float Xa4 = fmaf(r00, mu4_, -gx), Ya4 = fmaf(r10, mu4_, -gy), Za4 = fmaf(r20, mu4_, -gz);

    // Keep-alive: force materialization of all loop-invariant values.
    asm volatile("" ::
        "v"(cA0),"v"(cA1),"v"(cA2),"v"(cA3),"v"(cA4),
        "v"(cB0),"v"(cB1),"v"(cB2),"v"(cB3),"v"(cB4),
        "v"(cC0),"v"(cC1),"v"(cC2),"v"(cC3),"v"(cC4),
        "v"(Xa0),"v"(Xa1),"v"(Xa2),"v"(Xa3),"v"(Xa4),
        "v"(Ya0),"v"(Ya1),"v"(Ya2),"v"(Ya3),"v"(Ya4),
        "v"(Za0),"v"(Za1),"v"(Za2),"v"(Za3),"v"(Za4),
        "v"(fyA),"v"(fyB),"v"(fyC));

    float mv0_ = 0.5f * (float)(n2 - 600) - 95.25f;
    float mv1_ = 0.5f * (float)(n2 - 599) - 95.25f;
    float mv2_ = 0.5f * (float)(n2 - 598) - 95.25f;
    float mv3_ = 0.5f * (float)(n2 - 597) - 95.25f;
    float mv4_ = 0.5f * (float)(n2 - 596) - 95.25f;

    float acc0 = 0.0f, acc1 = 0.0f;
    ATS_ROW(SEL_J0, fyA, mv0_)
    ATS_ROW(SEL_J1, fyB, mv1_)
    ATS_ROW(SEL_J2, fyC, mv2_)
    ATS_ROW(SEL_J3, fyA, mv3_)
    ATS_ROW(SEL_J4, fyB, mv4_)

    atomicAdd(&outvol[(z << 14) + yx], acc0 + acc1);
}

// p = r; Ap = 0; rr0 += r^2   [slab-skipped, block-uniform]
__global__ __launch_bounds__(256) void initpr_kernel(
    const float* __restrict__ r, float* __restrict__ p, float* __restrict__ Ap,
    double* __restrict__ rr_slots, const int* __restrict__ zb)
{
    int z = blockIdx.x >> 6;
    if (z < zb[0] || z > zb[1]) return;
    int i = blockIdx.x * 256 + threadIdx.x;
    float rv = r[i];
    p[i] = rv;
    Ap[i] = 0.0f;
    block_reduce_spread((double)rv * (double)rv, rr_slots);
}

// ---------------------------------------------------------------------------
// Fused dots + CG update with in-kernel device-scope sync.
// Phase 1: {pAp, rAp, ApAp} over slab (grid-stride). Arrive on ctr.
// Block 0 waits for all arrivals, reduces the 64 slots, computes
// alpha/beta/rr_new, publishes via abf + flag. All blocks then run the
// update phase. DEADLOCK SAFETY: grid = 1024 blocks x 256 thr = 4096 waves
// = 16 waves/CU (cap 32), VGPR well under limit -> all blocks co-resident
// by construction; every block arrives before any spin can starve.
// ctr/flag/abf live in paps[1..3] (slot indices are multiples of 32; the
// gap is zeroed by every iteration's a_kernel BEFORE this kernel runs).
// ---------------------------------------------------------------------------
__global__ __launch_bounds__(256) void dots_update_kernel(
    float* __restrict__ x, float* __restrict__ r, float* __restrict__ p,
    float* __restrict__ Ap,
    const double* __restrict__ rr_src, int rr_is_slots,
    double* __restrict__ paps, double* __restrict__ raps,
    double* __restrict__ apaps, double* __restrict__ rr_out,
    const int* __restrict__ zb, float* __restrict__ outp)
{
    int tid = threadIdx.x;
    int zlo = zb[0], zhi = zb[1];
    int b0 = zlo << 6, b1 = (zhi + 1) << 6;

    unsigned long long* ctr  = (unsigned long long*)(paps + 1);
    unsigned long long* flag = (unsigned long long*)(paps + 2);
    float* abf = (float*)(paps + 3);

    // ---- Phase 1: dots over slab ----
    double s0 = 0.0, s1 = 0.0, s2 = 0.0;
    for (int vb = b0 + (int)blockIdx.x; vb < b1; vb += (int)gridDim.x) {
        int i = vb * 256 + tid;
        double a = (double)Ap[i];
        s0 += a * (double)p[i];
        s1 += a * (double)r[i];
        s2 += a * a;
    }
    #pragma unroll
    for (int off = 32; off > 0; off >>= 1) {
        s0 += __shfl_down(s0, off, 64);
        s1 += __shfl_down(s1, off, 64);
        s2 += __shfl_down(s2, off, 64);
    }
    __shared__ double ls3[12];
    __shared__ float sh_ab[2];
    int wid = tid >> 6;
    if ((tid & 63) == 0) {
        ls3[wid*3+0] = s0; ls3[wid*3+1] = s1; ls3[wid*3+2] = s2;
    }
    __syncthreads();
    if (tid == 0) {
        int sl = (blockIdx.x & 63) * 32;
        atomicAdd(&paps[sl],  ls3[0]+ls3[3]+ls3[6]+ls3[9]);
        atomicAdd(&raps[sl],  ls3[1]+ls3[4]+ls3[7]+ls3[10]);
        atomicAdd(&apaps[sl], ls3[2]+ls3[5]+ls3[8]+ls3[11]);
        __threadfence();
        __hip_atomic_fetch_add(ctr, 1ull, __ATOMIC_RELEASE,
                               __HIP_MEMORY_SCOPE_AGENT);
    }

    // ---- Sync + scalar finalize ----
    if (blockIdx.x == 0) {
        if (tid == 0) {
            while (__hip_atomic_load(ctr, __ATOMIC_ACQUIRE,
                                     __HIP_MEMORY_SCOPE_AGENT)
                   < (unsigned long long)gridDim.x)
                __builtin_amdgcn_s_sleep(8);
            __threadfence();
        }
        __syncthreads();
        if (tid < 64) {
            double v0 = rr_is_slots ? rr_src[tid * 32] : 0.0;
            double v1 = paps[tid * 32];
            double v2 = raps[tid * 32];
            double v3 = apaps[tid * 32];
            #pragma unroll
            for (int off = 32; off > 0; off >>= 1) {
                v0 += __shfl_down(v0, off, 64);
                v1 += __shfl_down(v1, off, 64);
                v2 += __shfl_down(v2, off, 64);
                v3 += __shfl_down(v3, off, 64);
            }
            if (tid == 0) {
                double rr_old = rr_is_slots ? v0 : rr_src[0];
                double alpha = rr_old / v1;
                double rr_new = rr_old - 2.0 * alpha * v2 + alpha * alpha * v3;
                rr_out[0] = rr_new;
                float af = (float)alpha;
                float bf = (float)(rr_new / rr_old);
                abf[0] = af; abf[1] = bf;
                sh_ab[0] = af; sh_ab[1] = bf;
                __threadfence();
                __hip_atomic_store(flag, 1ull, __ATOMIC_RELEASE,
                                   __HIP_MEMORY_SCOPE_AGENT);
            }
        }
        __syncthreads();
    } else {
        if (tid == 0) {
            while (__hip_atomic_load(flag, __ATOMIC_ACQUIRE,
                                     __HIP_MEMORY_SCOPE_AGENT) == 0ull)
                __builtin_amdgcn_s_sleep(8);
            __threadfence();
            sh_ab[0] = abf[0]; sh_ab[1] = abf[1];
        }
        __syncthreads();
    }
    float af = sh_ab[0], bf = sh_ab[1];

    // ---- Phase 2: update over slab ----
    for (int vb = b0 + (int)blockIdx.x; vb < b1; vb += (int)gridDim.x) {
        int i = vb * 256 + tid;
        float xv = fmaf(af, p[i], x[i]);
        x[i] = xv;
        float apv = Ap[i];
        Ap[i] = 0.0f;
        float rvv = fmaf(-af, apv, r[i]);
        r[i] = rvv;
        p[i] = fmaf(bf, p[i], rvv);
        if (outp) outp[i] = fmaxf(xv, 0.0f);
    }
    if (outp) {   // out-of-slab passthrough: relu(x) (x untouched there)
        for (int vb = (int)blockIdx.x; vb < b0; vb += (int)gridDim.x) {
            int i = vb * 256 + tid;
            outp[i] = fmaxf(x[i], 0.0f);
        }
        for (int vb = b1 + (int)blockIdx.x; vb < VOX / 256; vb += (int)gridDim.x) {
            int i = vb * 256 + tid;
            outp[i] = fmaxf(x[i], 0.0f);
        }
    }
}

extern "C" void kernel_launch(void* const* d_in, const int* in_sizes, int n_in,
                              void* d_out, int out_size, void* d_ws, size_t ws_size,
                              hipStream_t stream) {
    const float* theta  = (const float*)d_in[0];  // [16,3,4]
    const float* slices = (const float*)d_in[1];  // [16,1,128,128]
    const float* volume = (const float*)d_in[2];  // [1,1,128,128,128]
    const float* psf    = (const float*)d_in[3];  // [3,3,3]
    float* out = (float*)d_out;

    char* ws = (char*)d_ws;
    float* x  = (float*)ws;
    float* r  = x  + VOX;     // r and p contiguous (single memset covers both)
    float* p  = r  + VOX;
    float* Ap = p  + VOX;
    float* sl = Ap + VOX;
    double* sc = (double*)(sl + NPIX);
    double* rrs0  = sc;             // 64 slots * stride 32 doubles (16 KB)
    double* paps  = sc + 2048;      // [1..7] gap: fused-kernel ctr/flag/abf
    double* raps  = sc + 4096;
    double* apaps = sc + 6144;
    double* rr_sc = sc + 8192;      // rr chain scalars [0..10]
    float* cst = (float*)(sc + 8208);        // 16*128 floats + 9 globals
    int* zb = (int*)(cst + NS * CSTR + 16);  // [zlo, zhi]

    const int gapix = NPIX / 64;        // 4096 (a_kernel: 64-thread blocks)
    const int gvox = VOX / 256;         // 8192
    const int gsc  = NPIX * ZSL / 256;  // 5120 (at_scatter: thread per (x,y,n,zi))
    const int gdu  = 1024;              // fused dots+update (co-resident!)

    prep_kernel<<<1, 512, 0, stream>>>(theta, psf, cst, zb);

    // x = volume; r = p = 0 (exact zeros; r is at_scatter's first target)
    hipMemcpyAsync(x, volume, VOX * sizeof(float), hipMemcpyDeviceToDevice, stream);
    hipMemsetAsync(r, 0, 2 * VOX * sizeof(float), stream);

    // sl = slices - A(x0)   (a_kernel zeroes rrs0)
    a_kernel<<<gapix, 64, 0, stream>>>(cst, x, psf, sl, slices, rrs0, nullptr, nullptr);
    // r += At(sl) = b - AtA x0  (scatter into zeroed r)
    at_scatter_kernel<<<gsc, 256, 0, stream>>>(cst, sl, r);
    // p = r; Ap = 0; rr0 = dot(r,r)
    initpr_kernel<<<gvox, 256, 0, stream>>>(r, p, Ap, rrs0, zb);

    for (int it = 0; it < 10; ++it) {
        // a_kernel zeroes the three dot-slot arrays incl. ctr/flag/abf gap
        a_kernel<<<gapix, 64, 0, stream>>>(cst, p, psf, sl, nullptr, paps, raps, apaps);
        // Ap += At(A p)   (Ap zeroed by initpr / previous update phase)
        at_scatter_kernel<<<gsc, 256, 0, stream>>>(cst, sl, Ap);
        // fused {pAp,rAp,ApAp} -> alpha/beta -> update
        const double* rr_src = (it == 0) ? rrs0 : &rr_sc[it];
        dots_update_kernel<<<gdu, 256, 0, stream>>>(
            x, r, p, Ap, rr_src, (it == 0) ? 1 : 0,
            paps, raps, apaps, &rr_sc[it + 1], zb, (it == 9) ? out : nullptr);
    }
}

// Round 6
// 1015.831 us; speedup vs baseline: 2.1581x; 2.1581x over previous
//
#include <hip/hip_runtime.h>
#include <math.h>

constexpr int VOX = 128 * 128 * 128;     // 2,097,152
constexpr int NPIX = 16 * 128 * 128;     // 262,144
constexpr int NS = 16;
constexpr float RES_RATIO = 1.5f;
constexpr int CSTR = 128;
// a_kernel LDS tile dims (provable bounds: x,y extent <= 18.1, z <= 8.1)
constexpr int TNX = 19, TNY = 19, TNZ = 10;
// at_scatter z-slots per column: window length 2*lim/r22 <= 4.55 -> <=5 ints
constexpr int ZSL = 5;

// Per-slice constant block (floats, stride 128):
//  [0..11]  T row-major  [12..14] tc=t+63.5  [15..17] col L1 norms
//  [18..20] row L1 norms [21..22] z slab     [24+3k..] rotated PSF offsets
//  [105..109] at_scatter hoists: lim, 1/r22, -r20*tc2, -r21*tc2, -r22*tc2
// Globals at cst+NS*CSTR: separable psf fx[3],fy[3],fz[3] (1/c^2 in fz)
// NOTE (R5 lesson): in-kernel grid sync via agent-scope atomics cost ~145us
// per use on MI355X (vs ~10-15us for a kernel-boundary pair) — do NOT fuse
// reduction->broadcast phases into one kernel here.

__global__ __launch_bounds__(512) void prep_kernel(
    const float* __restrict__ theta, const float* __restrict__ psf,
    float* __restrict__ cst, int* __restrict__ zb)
{
    int tid = threadIdx.x;
    int n = tid >> 5, j = tid & 31;
    if (n < NS) {
        const float* T = theta + n * 12;
        float* C = cst + n * CSTR;
        if (j < 12) C[j] = T[j];
        if (j == 12) {
            float r00=T[0], r01=T[1], r02=T[2],  t0=T[3];
            float r10=T[4], r11=T[5], r12=T[6],  t1=T[7];
            float r20=T[8], r21=T[9], r22=T[10], t2=T[11];
            float tc0 = t0 + 63.5f, tc1 = t1 + 63.5f, tc2 = t2 + 63.5f;
            C[12]=tc0; C[13]=tc1; C[14]=tc2;
            float C2 = fabsf(r02)+fabsf(r12)+fabsf(r22);
            C[15] = fabsf(r00)+fabsf(r10)+fabsf(r20);
            C[16] = fabsf(r01)+fabsf(r11)+fabsf(r21);
            C[17] = C2;
            C[18] = fabsf(r00)+fabsf(r01)+fabsf(r02);
            C[19] = fabsf(r10)+fabsf(r11)+fabsf(r12);
            C[20] = fabsf(r20)+fabsf(r21)+fabsf(r22);
            // conservative slab (covers at_scatter's widened per-column ranges)
            float mx = fmaxf(tc0, 127.0f - tc0);
            float my = fmaxf(tc1, 127.0f - tc1);
            float marg = 1.05f + C2 + fabsf(r02)*mx + fabsf(r12)*my;
            float inv = 1.0f / fabsf(r22);
            C[21] = tc2 - marg * inv;
            C[22] = tc2 + marg * inv;
            // at_scatter per-thread hoists (bitwise-equal expressions)
            C[105] = 1.0f + C2 + 0.01f;      // lim
            C[106] = 1.0f / r22;             // inv22 (r22 > 0 always)
            C[107] = -(r20 * tc2);           // ax const
            C[108] = -(r21 * tc2);           // ay const
            C[109] = -(r22 * tc2);           // az const
        }
        if (j < 27) {
            float ox = (float)(j % 3) - 1.0f;
            float oy = (float)((j / 3) % 3) - 1.0f;
            float oz = (float)(j / 9) - 1.0f;
            C[24 + 3*j + 0] = T[0]*ox + T[1]*oy + T[2]*oz;
            C[24 + 3*j + 1] = T[4]*ox + T[5]*oy + T[6]*oz;
            C[24 + 3*j + 2] = T[8]*ox + T[9]*oy + T[10]*oz;
        }
    }
    __syncthreads();
    if (tid == 0) {
        float zmin = 1e30f, zmax = -1e30f;
        for (int s = 0; s < NS; ++s) {
            zmin = fminf(zmin, cst[s * CSTR + 21]);
            zmax = fmaxf(zmax, cst[s * CSTR + 22]);
        }
        zb[0] = max(0, (int)floorf(zmin));
        zb[1] = min(127, (int)ceilf(zmax));
        float* G = cst + NS * CSTR;
        float c = psf[13];
        float ic2 = 1.0f / (c * c);
        G[0]=psf[12]; G[1]=psf[13]; G[2]=psf[14];
        G[3]=psf[10]; G[4]=psf[13]; G[5]=psf[16];
        G[6]=psf[4]*ic2; G[7]=psf[13]*ic2; G[8]=psf[22]*ic2;
    }
}

// ---------------------------------------------------------------------------
// Reductions: 64 spread slots (stride 32 doubles). Contain __syncthreads():
// only block-uniform early returns may precede them.
// ---------------------------------------------------------------------------
__device__ __forceinline__ void block_reduce_spread(double s, double* slots)
{
    #pragma unroll
    for (int off = 32; off > 0; off >>= 1)
        s += __shfl_down(s, off, 64);
    __shared__ double ls[4];
    if ((threadIdx.x & 63) == 0) ls[threadIdx.x >> 6] = s;
    __syncthreads();
    if (threadIdx.x == 0)
        atomicAdd(&slots[(blockIdx.x & 63) * 32], ls[0] + ls[1] + ls[2] + ls[3]);
}

__device__ __forceinline__ void block_reduce3(
    double s0, double s1, double s2, double* a0, double* a1, double* a2)
{
    #pragma unroll
    for (int off = 32; off > 0; off >>= 1) {
        s0 += __shfl_down(s0, off, 64);
        s1 += __shfl_down(s1, off, 64);
        s2 += __shfl_down(s2, off, 64);
    }
    __shared__ double ls3[12];
    int wid = threadIdx.x >> 6;
    if ((threadIdx.x & 63) == 0) {
        ls3[wid*3+0] = s0; ls3[wid*3+1] = s1; ls3[wid*3+2] = s2;
    }
    __syncthreads();
    if (threadIdx.x == 0) {
        int sl = (blockIdx.x & 63) * 32;
        atomicAdd(&a0[sl], ls3[0]+ls3[3]+ls3[6]+ls3[9]);
        atomicAdd(&a1[sl], ls3[1]+ls3[4]+ls3[7]+ls3[10]);
        atomicAdd(&a2[sl], ls3[2]+ls3[5]+ls3[8]+ls3[11]);
    }
}

// ---------------------------------------------------------------------------
// A: PSF-weighted trilinear gather, LDS-tiled (64-thread blocks, 8x8 patch).
// If subsrc != null: out = subsrc - A(vol). Block 0 zeroes slot arrays.
// Staging loop uses an incremental (gx,gy,gz) walk (step 64 = +7 x, +3 y,
// carries) instead of per-iteration div/mod by 19 — verified equivalent.
// ---------------------------------------------------------------------------
__global__ __launch_bounds__(64, 4) void a_kernel(
    const float* __restrict__ cst, const float* __restrict__ vol,
    const float* __restrict__ psf, float* __restrict__ out,
    const float* __restrict__ subsrc,
    double* __restrict__ z1, double* __restrict__ z2, double* __restrict__ z3)
{
    int tid = threadIdx.x;
    if (blockIdx.x == 0) {
        for (int i = tid; i < 2048; i += 64) {
            if (z1) z1[i] = 0.0;
            if (z2) z2[i] = 0.0;
            if (z3) z3[i] = 0.0;
        }
    }

    int b = blockIdx.x;              // 4096 blocks: n = b>>8, patch = b&255
    int n = b >> 8;
    int pb = b & 255;
    int w0 = (pb & 15) << 3, h0 = (pb >> 4) << 3;
    int w = w0 + (tid & 7), h = h0 + (tid >> 3);
    int oidx = (n << 14) + (h << 7) + w;
    float base = subsrc ? subsrc[oidx] : 0.0f;
    float sgn = subsrc ? -1.0f : 1.0f;

    const float* C = cst + n * CSTR;
    float r00=C[0], r01=C[1];
    float r10=C[4], r11=C[5];
    float r20=C[8], r21=C[9];

    float uc = (w0 + 3.5f - 63.5f) * RES_RATIO;
    float vc = (h0 + 3.5f - 63.5f) * RES_RATIO;
    const float du = 5.25f, dv = 5.25f;
    float cx = r00*uc + r01*vc + C[12];
    float cy = r10*uc + r11*vc + C[13];
    float cz = r20*uc + r21*vc + C[14];
    float hx = fabsf(r00)*du + fabsf(r01)*dv + C[18];
    float hy = fabsf(r10)*du + fabsf(r11)*dv + C[19];
    float hz = fabsf(r20)*du + fabsf(r21)*dv + C[20];
    int tx0 = (int)floorf(cx - hx);
    int ty0 = (int)floorf(cy - hy);
    int tz0 = (int)floorf(cz - hz);

    if (tx0 >= 128 || tx0 + TNX <= 0 || ty0 >= 128 || ty0 + TNY <= 0 ||
        tz0 >= 128 || tz0 + TNZ <= 0) {
        out[oidx] = base;
        return;
    }

    __shared__ float tile[TNZ * TNY * TNX];
    {
        int gx = tx0 + tid % TNX;
        int gy = ty0 + tid / TNX;
        int gz = tz0;
        const int gxe = tx0 + TNX, gye = ty0 + TNY;
        for (int i = tid; i < TNZ * TNY * TNX; i += 64) {
            bool ok = ((unsigned)gx < 128u) & ((unsigned)gy < 128u) & ((unsigned)gz < 128u);
            int off = ok ? ((gz << 14) + (gy << 7) + gx) : 0;
            float v = vol[off];
            tile[i] = ok ? v : 0.0f;
            gx += 7; gy += 3;                  // step 64 = 3*19 + 7
            if (gx >= gxe) { gx -= TNX; gy += 1; }
            if (gy >= gye) { gy -= TNY; gz += 1; }
        }
    }
    __syncthreads();

    float u = (w - 63.5f) * RES_RATIO;
    float v = (h - 63.5f) * RES_RATIO;
    float px = fmaf(r00, u, fmaf(r01, v, C[12])) - (float)tx0;
    float py = fmaf(r10, u, fmaf(r11, v, C[13])) - (float)ty0;
    float pz = fmaf(r20, u, fmaf(r21, v, C[14])) - (float)tz0;

    const float* O = C + 24;
    float acc = 0.0f;
    for (int k = 0; k < 27; ++k) {
        float sx = px + O[3*k+0];
        float sy = py + O[3*k+1];
        float sz = pz + O[3*k+2];
        int x0 = (int)sx, y0 = (int)sy, z0 = (int)sz;
        float fx = sx - (float)x0, fy = sy - (float)y0, fz = sz - (float)z0;
        const float* tp = tile + (z0 * TNY + y0) * TNX + x0;
        float c000 = tp[0],             c001 = tp[1];
        float c010 = tp[TNX],           c011 = tp[TNX+1];
        float c100 = tp[TNY*TNX],       c101 = tp[TNY*TNX+1];
        float c110 = tp[TNY*TNX+TNX],   c111 = tp[TNY*TNX+TNX+1];
        float c00 = fmaf(fx, c001 - c000, c000);
        float c01 = fmaf(fx, c011 - c010, c010);
        float c10 = fmaf(fx, c101 - c100, c100);
        float c11 = fmaf(fx, c111 - c110, c110);
        float c0  = fmaf(fy, c01 - c00, c00);
        float c1  = fmaf(fy, c11 - c10, c10);
        acc = fmaf(psf[k], fmaf(fz, c1 - c0, c0), acc);
    }
    out[oidx] = fmaf(sgn, acc, base);
}

// ---------------------------------------------------------------------------
// At, z-split scatter (arithmetic unchanged since R2; contributions bitwise-
// identical). PSF symmetry (pfx0==pfx2, pfy0==pfy2 bitwise: Gaussian, (+-1)^2
// computed identically on host) lets fx/fy selects collapse to 1 cndmask —
// selection among bitwise-equal values, exact.
// ~1.2M atomicAdds total; outvol must be pre-zeroed. No barriers.
// ---------------------------------------------------------------------------
#define ATS_CL(B_) fmaxf(1.0f - fabsf(B_), 0.0f)
#define ATS_PT(cAi, cBi, cCi, Xai, Yai, Zai, SEL, fyj, mvj, ACC) { \
    float sf_  = SEL(cAi, cBi, cCi); \
    float svf_ = sf_ * fyj; \
    float Bx_ = fmaf(r01, mvj, Xai); \
    float By_ = fmaf(r11, mvj, Yai); \
    float Bz_ = fmaf(r21, mvj, Zai); \
    float w0_ = ATS_CL(Bx_ - r02) * ATS_CL(By_ - r12) * ATS_CL(Bz_ - r22); \
    float w1_ = ATS_CL(Bx_) * ATS_CL(By_) * ATS_CL(Bz_); \
    float w2_ = ATS_CL(Bx_ + r02) * ATS_CL(By_ + r12) * ATS_CL(Bz_ + r22); \
    float t_  = fmaf(w0_, pfz0, fmaf(w1_, pfz1, w2_ * pfz2)); \
    ACC = fmaf(t_, svf_, ACC); }
#define ATS_ROW(SEL, fyj, mvj) \
    ATS_PT(cA0,cB0,cC0, Xa0,Ya0,Za0, SEL, fyj, mvj, acc0) \
    ATS_PT(cA1,cB1,cC1, Xa1,Ya1,Za1, SEL, fyj, mvj, acc1) \
    ATS_PT(cA2,cB2,cC2, Xa2,Ya2,Za2, SEL, fyj, mvj, acc0) \
    ATS_PT(cA3,cB3,cC3, Xa3,Ya3,Za3, SEL, fyj, mvj, acc1) \
    ATS_PT(cA4,cB4,cC4, Xa4,Ya4,Za4, SEL, fyj, mvj, acc0)
#define SEL_J0(a,b,c) (mj1 ? (b) : (a))
#define SEL_J1(a,b,c) (mj1 ? (a) : (b))
#define SEL_J2(a,b,c) (mj1 ? (b) : (mj2 ? (c) : (a)))
#define SEL_J3(a,b,c) (mj1 ? (c) : (b))
#define SEL_J4(a,b,c) (mj1 ? (b) : (c))

__global__ __launch_bounds__(256, 4) void at_scatter_kernel(
    const float* __restrict__ cst, const float* __restrict__ sl,
    float* __restrict__ outvol)
{
    int id = blockIdx.x * 256 + threadIdx.x;    // exact grid: NPIX*ZSL threads
    int x = id & 127, y = (id >> 7) & 127;
    int n = (id >> 14) & 15, zi = id >> 18;     // n, zi block-uniform
    const float* C = cst + n * CSTR;
    float r00=C[0], r01=C[1], r02=C[2];
    float r10=C[4], r11=C[5], r12=C[6];
    float r20=C[8], r21=C[9], r22=C[10];
    float tc2 = C[14];
    float C0=C[15], C1=C[16];

    float gx = (float)x - C[12];
    float gy = (float)y - C[13];

    // gpz(z) = az + r22*z ; active: |gpz| < lim. r22 > 0 always.
    float az = r02*gx + r12*gy + C[109];
    float lim = C[105];
    float inv22 = C[106];
    int z0 = (int)ceilf((-lim - az) * inv22);
    int z1v = (int)floorf(( lim - az) * inv22);
    z0 = max(z0, 0); z1v = min(z1v, 127);
    int z = z0 + zi;
    if (z > z1v) return;                        // no barriers: safe

    float ax = r00*gx + r10*gy + C[107];        // gpx = ax + r20*z
    float ay = r01*gx + r11*gy + C[108];        // gpy = ay + r21*z

    float fzv = (float)z;
    float gpx = fmaf(r20, fzv, ax);
    float gpy = fmaf(r21, fzv, ay);
    float gz  = fzv - tc2;
    int m2 = (int)floorf(2.0f*(gpx + 95.25f - C0)) + 601;
    int n2 = (int)floorf(2.0f*(gpy + 95.25f - C1)) + 601;
    int wb0 = m2 / 3;                           // biased by 200 (per-z anchor)
    int hb0 = n2 / 3;
    int ki0 = m2 - wb0 * 3;
    int kj0 = n2 - hb0 * 3;

    // 3x3 sval register block, OOB-masked (per-z anchor => ci,rj in 0..2)
    const float* slice_n = sl + (n << 14);
    float s[3][3];
    #pragma unroll
    for (int aa = 0; aa < 3; ++aa) {
        int hv = hb0 - 200 + aa;
        bool hok = ((unsigned)hv < 128u);
        #pragma unroll
        for (int cc = 0; cc < 3; ++cc) {
            int wv = wb0 - 200 + cc;
            bool ok = hok & ((unsigned)wv < 128u);
            int off = ok ? ((hv << 7) + wv) : 0;
            float vs = slice_n[off];
            s[aa][cc] = ok ? vs : 0.0f;
        }
    }

    const float* G = cst + NS * CSTR;
    float pfx0=G[0], pfx1=G[1];
    float pfy0=G[3], pfy1=G[4];
    float pfz0=G[6], pfz1=G[7], pfz2=G[8];

    int yx = (y << 7) + x;

    bool mi0 = (ki0 == 0), mi1 = (ki0 == 1), mi2 = (ki0 == 2);
    bool mj0 = (kj0 == 0), mj1 = (kj0 == 1), mj2 = (kj0 == 2);

    // fx values (period 3; pfx0==pfx2 bitwise -> single selects)
    float fxA = mi0 ? pfx1 : pfx0;
    float fxB = mi2 ? pfx1 : pfx0;
    float fxC = mi1 ? pfx1 : pfx0;

    float fyA = mj0 ? pfy1 : pfy0;
    float fyB = mj2 ? pfy1 : pfy0;
    float fyC = mj1 ? pfy1 : pfy0;

    // Column-selected s-values per i (R2 tables), premultiplied by fx.
    float cA0 = (mi1 ? s[0][1] : s[0][0]) * fxA;
    float cB0 = (mi1 ? s[1][1] : s[1][0]) * fxA;
    float cC0 = (mi1 ? s[2][1] : s[2][0]) * fxA;
    float cA1 = (mi1 ? s[0][0] : s[0][1]) * fxB;
    float cB1 = (mi1 ? s[1][0] : s[1][1]) * fxB;
    float cC1 = (mi1 ? s[2][0] : s[2][1]) * fxB;
    float cA2 = (mi1 ? s[0][1] : (mi2 ? s[0][2] : s[0][0])) * fxC;
    float cB2 = (mi1 ? s[1][1] : (mi2 ? s[1][2] : s[1][0])) * fxC;
    float cC2 = (mi1 ? s[2][1] : (mi2 ? s[2][2] : s[2][0])) * fxC;
    float cA3 = (mi1 ? s[0][2] : s[0][1]) * fxA;
    float cB3 = (mi1 ? s[1][2] : s[1][1]) * fxA;
    float cC3 = (mi1 ? s[2][2] : s[2][1]) * fxA;
    float cA4 = (mi1 ? s[0][1] : s[0][2]) * fxB;
    float cB4 = (mi1 ? s[1][1] : s[1][2]) * fxB;
    float cC4 = (mi1 ? s[2][1] : s[2][2]) * fxB;

    float mu0_ = 0.5f * (float)(m2 - 600) - 95.25f;
    float mu1_ = 0.5f * (float)(m2 - 599) - 95.25f;
    float mu2_ = 0.5f * (float)(m2 - 598) - 95.25f;
    float mu3_ = 0.5f * (float)(m2 - 597) - 95.25f;
    float mu4_ = 0.5f * (float)(m2 - 596) - 95.25f;
    float Xa0 = fmaf(r00, mu0_, -gx), Ya0 = fmaf(r10, mu0_, -gy), Za0 = fmaf(r20, mu0_, -gz);
    float Xa1 = fmaf(r00, mu1_, -gx), Ya1 = fmaf(r10, mu1_, -gy), Za1 = fmaf(r20, mu1_, -gz);
    float Xa2 = fmaf(r00, mu2_, -gx), Ya2 = fmaf(r10, mu2_, -gy), Za2 = fmaf(r20, mu2_, -gz);
    float Xa3 = fmaf(r00, mu3_, -gx), Ya3 = fmaf(r10, mu3_, -gy), Za3 = fmaf(r20, mu3_, -gz);
    float Xa4 = fmaf(r00, mu4_, -gx), Ya4 = fmaf(r10, mu4_, -gy), Za4 = fmaf(r20, mu4_, -gz);

    // Keep-alive: force materialization of all loop-invariant values.
    asm volatile("" ::
        "v"(cA0),"v"(cA1),"v"(cA2),"v"(cA3),"v"(cA4),
        "v"(cB0),"v"(cB1),"v"(cB2),"v"(cB3),"v"(cB4),
        "v"(cC0),"v"(cC1),"v"(cC2),"v"(cC3),"v"(cC4),
        "v"(Xa0),"v"(Xa1),"v"(Xa2),"v"(Xa3),"v"(Xa4),
        "v"(Ya0),"v"(Ya1),"v"(Ya2),"v"(Ya3),"v"(Ya4),
        "v"(Za0),"v"(Za1),"v"(Za2),"v"(Za3),"v"(Za4),
        "v"(fyA),"v"(fyB),"v"(fyC));

    float mv0_ = 0.5f * (float)(n2 - 600) - 95.25f;
    float mv1_ = 0.5f * (float)(n2 - 599) - 95.25f;
    float mv2_ = 0.5f * (float)(n2 - 598) - 95.25f;
    float mv3_ = 0.5f * (float)(n2 - 597) - 95.25f;
    float mv4_ = 0.5f * (float)(n2 - 596) - 95.25f;

    float acc0 = 0.0f, acc1 = 0.0f;
    ATS_ROW(SEL_J0, fyA, mv0_)
    ATS_ROW(SEL_J1, fyB, mv1_)
    ATS_ROW(SEL_J2, fyC, mv2_)
    ATS_ROW(SEL_J3, fyA, mv3_)
    ATS_ROW(SEL_J4, fyB, mv4_)

    atomicAdd(&outvol[(z << 14) + yx], acc0 + acc1);
}

// p = r; Ap = 0; rr0 += r^2   [slab-skipped, block-uniform]
__global__ __launch_bounds__(256) void initpr_kernel(
    const float* __restrict__ r, float* __restrict__ p, float* __restrict__ Ap,
    double* __restrict__ rr_slots, const int* __restrict__ zb)
{
    int z = blockIdx.x >> 6;
    if (z < zb[0] || z > zb[1]) return;
    int i = blockIdx.x * 256 + threadIdx.x;
    float rv = r[i];
    p[i] = rv;
    Ap[i] = 0.0f;
    block_reduce_spread((double)rv * (double)rv, rr_slots);
}

// {pAp, rAp, ApAp} over the slab
__global__ __launch_bounds__(256) void dots_kernel(
    const float* __restrict__ Ap, const float* __restrict__ p,
    const float* __restrict__ r,
    double* __restrict__ s_pap, double* __restrict__ s_rap,
    double* __restrict__ s_apap, const int* __restrict__ zb)
{
    int z = blockIdx.x >> 6;
    if (z < zb[0] || z > zb[1]) return;
    int i = blockIdx.x * 256 + threadIdx.x;
    double a = (double)Ap[i];
    block_reduce3(a * (double)p[i], a * (double)r[i], a * a,
                  s_pap, s_rap, s_apap);
}

// ---------------------------------------------------------------------------
// Merged CG update: alpha = rr_old/pAp; rr_new = rr_old - 2a*rAp + a^2*ApAp;
// beta = rr_new/rr_old; x += a p; r -= a Ap; p = r + beta p; Ap = 0 (for the
// next iteration's scatter).
// ---------------------------------------------------------------------------
__global__ __launch_bounds__(256) void update_kernel(
    float* __restrict__ x, float* __restrict__ r, float* __restrict__ p,
    float* __restrict__ Ap,
    const double* __restrict__ rr_src, int rr_is_slots,
    const double* __restrict__ paps, const double* __restrict__ raps,
    const double* __restrict__ apaps, double* __restrict__ rr_out,
    const int* __restrict__ zb, float* __restrict__ outp)
{
    __shared__ float sh_ab[2];
    int tid = threadIdx.x;
    if (tid < 64) {
        double v0 = rr_is_slots ? rr_src[tid * 32] : 0.0;
        double v1 = paps[tid * 32];
        double v2 = raps[tid * 32];
        double v3 = apaps[tid * 32];
        #pragma unroll
        for (int off = 32; off > 0; off >>= 1) {
            v0 += __shfl_down(v0, off, 64);
            v1 += __shfl_down(v1, off, 64);
            v2 += __shfl_down(v2, off, 64);
            v3 += __shfl_down(v3, off, 64);
        }
        if (tid == 0) {
            double rr_old = rr_is_slots ? v0 : rr_src[0];
            double alpha = rr_old / v1;
            double rr_new = rr_old - 2.0 * alpha * v2 + alpha * alpha * v3;
            if (blockIdx.x == 0) rr_out[0] = rr_new;
            sh_ab[0] = (float)alpha;
            sh_ab[1] = (float)(rr_new / rr_old);
        }
    }
    __syncthreads();
    float af = sh_ab[0], bf = sh_ab[1];

    int z = blockIdx.x >> 6;
    int i = blockIdx.x * 256 + tid;
    bool inslab = (z >= zb[0]) & (z <= zb[1]);
    if (!inslab) {
        if (outp) outp[i] = fmaxf(x[i], 0.0f);
        return;
    }
    float xv = fmaf(af, p[i], x[i]);
    x[i] = xv;
    float apv = Ap[i];
    Ap[i] = 0.0f;
    float rvv = fmaf(-af, apv, r[i]);
    r[i] = rvv;
    p[i] = fmaf(bf, p[i], rvv);
    if (outp) outp[i] = fmaxf(xv, 0.0f);
}

extern "C" void kernel_launch(void* const* d_in, const int* in_sizes, int n_in,
                              void* d_out, int out_size, void* d_ws, size_t ws_size,
                              hipStream_t stream) {
    const float* theta  = (const float*)d_in[0];  // [16,3,4]
    const float* slices = (const float*)d_in[1];  // [16,1,128,128]
    const float* volume = (const float*)d_in[2];  // [1,1,128,128,128]
    const float* psf    = (const float*)d_in[3];  // [3,3,3]
    float* out = (float*)d_out;

    char* ws = (char*)d_ws;
    float* x  = (float*)ws;
    float* r  = x  + VOX;     // r and p contiguous (single memset covers both)
    float* p  = r  + VOX;
    float* Ap = p  + VOX;
    float* sl = Ap + VOX;
    double* sc = (double*)(sl + NPIX);
    double* rrs0  = sc;             // 64 slots * stride 32 doubles (16 KB)
    double* paps  = sc + 2048;
    double* raps  = sc + 4096;
    double* apaps = sc + 6144;
    double* rr_sc = sc + 8192;      // rr chain scalars [0..10]
    float* cst = (float*)(sc + 8208);        // 16*128 floats + 9 globals
    int* zb = (int*)(cst + NS * CSTR + 16);  // [zlo, zhi]

    const int gapix = NPIX / 64;        // 4096 (a_kernel: 64-thread blocks)
    const int gvox = VOX / 256;         // 8192
    const int gsc  = NPIX * ZSL / 256;  // 5120 (at_scatter: thread per (x,y,n,zi))

    prep_kernel<<<1, 512, 0, stream>>>(theta, psf, cst, zb);

    // x = volume; r = p = 0 (exact zeros; r is at_scatter's first target)
    hipMemcpyAsync(x, volume, VOX * sizeof(float), hipMemcpyDeviceToDevice, stream);
    hipMemsetAsync(r, 0, 2 * VOX * sizeof(float), stream);

    // sl = slices - A(x0)   (a_kernel zeroes rrs0)
    a_kernel<<<gapix, 64, 0, stream>>>(cst, x, psf, sl, slices, rrs0, nullptr, nullptr);
    // r += At(sl) = b - AtA x0  (scatter into zeroed r)
    at_scatter_kernel<<<gsc, 256, 0, stream>>>(cst, sl, r);
    // p = r; Ap = 0; rr0 = dot(r,r)
    initpr_kernel<<<gvox, 256, 0, stream>>>(r, p, Ap, rrs0, zb);

    for (int it = 0; it < 10; ++it) {
        // a_kernel zeroes the three dot-slot arrays (consumers done)
        a_kernel<<<gapix, 64, 0, stream>>>(cst, p, psf, sl, nullptr, paps, raps, apaps);
        // Ap += At(A p)   (Ap zeroed by initpr / previous update)
        at_scatter_kernel<<<gsc, 256, 0, stream>>>(cst, sl, Ap);
        // {pAp, rAp, ApAp}
        dots_kernel<<<gvox, 256, 0, stream>>>(Ap, p, r, paps, raps, apaps, zb);

        const double* rr_src = (it == 0) ? rrs0 : &rr_sc[it];
        update_kernel<<<gvox, 256, 0, stream>>>(
            x, r, p, Ap, rr_src, (it == 0) ? 1 : 0,
            paps, raps, apaps, &rr_sc[it + 1], zb, (it == 9) ? out : nullptr);
    }
}

// Round 7
// 865.320 us; speedup vs baseline: 2.5334x; 1.1739x over previous
//
#include <hip/hip_runtime.h>
#include <math.h>

constexpr int VOX = 128 * 128 * 128;     // 2,097,152
constexpr int NPIX = 16 * 128 * 128;     // 262,144
constexpr int NS = 16;
constexpr float RES_RATIO = 1.5f;
constexpr int CSTR = 128;
// a_kernel LDS tile dims (provable bounds: x,y extent <= 18.1, z <= 8.1)
constexpr int TNX = 19, TNY = 19, TNZ = 10;
// at_scatter z-slots per column: window length 2*lim/r22 <= 4.55 -> <=5 ints
constexpr int ZSL = 5;

// Per-slice constant block (floats, stride 128):
//  [0..11]  T row-major  [12..14] tc=t+63.5  [15..17] col L1 norms
//  [18..20] row L1 norms [21..22] z slab     [24+3k..] rotated PSF offsets
//  [105..109] at_scatter hoists: lim, 1/r22, -r20*tc2, -r21*tc2, -r22*tc2
// Globals at cst+NS*CSTR: separable psf fx[3],fy[3],fz[3] (1/c^2 in fz)
// LESSONS (do not re-try):
//  - R5: in-kernel grid sync via agent-scope atomics costs ~145us per use
//    (vs ~10-15us kernel-boundary pair) — never fuse reduce->broadcast here.
//  - R6: incremental carry-walk staging in a_kernel serializes the 57
//    staging loads (loop-carried addr dependency) -> +147us total. Keep
//    div/mod staging: independent addresses preserve load pipelining.

__global__ __launch_bounds__(512) void prep_kernel(
    const float* __restrict__ theta, const float* __restrict__ psf,
    float* __restrict__ cst, int* __restrict__ zb)
{
    int tid = threadIdx.x;
    int n = tid >> 5, j = tid & 31;
    if (n < NS) {
        const float* T = theta + n * 12;
        float* C = cst + n * CSTR;
        if (j < 12) C[j] = T[j];
        if (j == 12) {
            float r00=T[0], r01=T[1], r02=T[2],  t0=T[3];
            float r10=T[4], r11=T[5], r12=T[6],  t1=T[7];
            float r20=T[8], r21=T[9], r22=T[10], t2=T[11];
            float tc0 = t0 + 63.5f, tc1 = t1 + 63.5f, tc2 = t2 + 63.5f;
            C[12]=tc0; C[13]=tc1; C[14]=tc2;
            float C2 = fabsf(r02)+fabsf(r12)+fabsf(r22);
            C[15] = fabsf(r00)+fabsf(r10)+fabsf(r20);
            C[16] = fabsf(r01)+fabsf(r11)+fabsf(r21);
            C[17] = C2;
            C[18] = fabsf(r00)+fabsf(r01)+fabsf(r02);
            C[19] = fabsf(r10)+fabsf(r11)+fabsf(r12);
            C[20] = fabsf(r20)+fabsf(r21)+fabsf(r22);
            // conservative slab (covers at_scatter's widened per-column ranges)
            float mx = fmaxf(tc0, 127.0f - tc0);
            float my = fmaxf(tc1, 127.0f - tc1);
            float marg = 1.05f + C2 + fabsf(r02)*mx + fabsf(r12)*my;
            float inv = 1.0f / fabsf(r22);
            C[21] = tc2 - marg * inv;
            C[22] = tc2 + marg * inv;
            // at_scatter per-thread hoists (bitwise-equal expressions)
            C[105] = 1.0f + C2 + 0.01f;      // lim
            C[106] = 1.0f / r22;             // inv22 (r22 > 0 always)
            C[107] = -(r20 * tc2);           // ax const
            C[108] = -(r21 * tc2);           // ay const
            C[109] = -(r22 * tc2);           // az const
        }
        if (j < 27) {
            float ox = (float)(j % 3) - 1.0f;
            float oy = (float)((j / 3) % 3) - 1.0f;
            float oz = (float)(j / 9) - 1.0f;
            C[24 + 3*j + 0] = T[0]*ox + T[1]*oy + T[2]*oz;
            C[24 + 3*j + 1] = T[4]*ox + T[5]*oy + T[6]*oz;
            C[24 + 3*j + 2] = T[8]*ox + T[9]*oy + T[10]*oz;
        }
    }
    __syncthreads();
    if (tid == 0) {
        float zmin = 1e30f, zmax = -1e30f;
        for (int s = 0; s < NS; ++s) {
            zmin = fminf(zmin, cst[s * CSTR + 21]);
            zmax = fmaxf(zmax, cst[s * CSTR + 22]);
        }
        zb[0] = max(0, (int)floorf(zmin));
        zb[1] = min(127, (int)ceilf(zmax));
        float* G = cst + NS * CSTR;
        float c = psf[13];
        float ic2 = 1.0f / (c * c);
        G[0]=psf[12]; G[1]=psf[13]; G[2]=psf[14];
        G[3]=psf[10]; G[4]=psf[13]; G[5]=psf[16];
        G[6]=psf[4]*ic2; G[7]=psf[13]*ic2; G[8]=psf[22]*ic2;
    }
}

// ---------------------------------------------------------------------------
// Reductions: 64 spread slots (stride 32 doubles). Contain __syncthreads():
// only block-uniform early returns may precede them.
// ---------------------------------------------------------------------------
__device__ __forceinline__ void block_reduce_spread(double s, double* slots)
{
    #pragma unroll
    for (int off = 32; off > 0; off >>= 1)
        s += __shfl_down(s, off, 64);
    __shared__ double ls[4];
    if ((threadIdx.x & 63) == 0) ls[threadIdx.x >> 6] = s;
    __syncthreads();
    if (threadIdx.x == 0)
        atomicAdd(&slots[(blockIdx.x & 63) * 32], ls[0] + ls[1] + ls[2] + ls[3]);
}

__device__ __forceinline__ void block_reduce3(
    double s0, double s1, double s2, double* a0, double* a1, double* a2)
{
    #pragma unroll
    for (int off = 32; off > 0; off >>= 1) {
        s0 += __shfl_down(s0, off, 64);
        s1 += __shfl_down(s1, off, 64);
        s2 += __shfl_down(s2, off, 64);
    }
    __shared__ double ls3[12];
    int wid = threadIdx.x >> 6;
    if ((threadIdx.x & 63) == 0) {
        ls3[wid*3+0] = s0; ls3[wid*3+1] = s1; ls3[wid*3+2] = s2;
    }
    __syncthreads();
    if (threadIdx.x == 0) {
        int sl = (blockIdx.x & 63) * 32;
        atomicAdd(&a0[sl], ls3[0]+ls3[3]+ls3[6]+ls3[9]);
        atomicAdd(&a1[sl], ls3[1]+ls3[4]+ls3[7]+ls3[10]);
        atomicAdd(&a2[sl], ls3[2]+ls3[5]+ls3[8]+ls3[11]);
    }
}

// ---------------------------------------------------------------------------
// A: PSF-weighted trilinear gather, LDS-tiled (64-thread blocks, 8x8 patch).
// If subsrc != null: out = subsrc - A(vol). Block 0 zeroes slot arrays.
// Staging uses div/mod addressing (independent per iteration -> loads
// pipeline; see R6 lesson above).
// ---------------------------------------------------------------------------
__global__ __launch_bounds__(64, 4) void a_kernel(
    const float* __restrict__ cst, const float* __restrict__ vol,
    const float* __restrict__ psf, float* __restrict__ out,
    const float* __restrict__ subsrc,
    double* __restrict__ z1, double* __restrict__ z2, double* __restrict__ z3)
{
    int tid = threadIdx.x;
    if (blockIdx.x == 0) {
        for (int i = tid; i < 2048; i += 64) {
            if (z1) z1[i] = 0.0;
            if (z2) z2[i] = 0.0;
            if (z3) z3[i] = 0.0;
        }
    }

    int b = blockIdx.x;              // 4096 blocks: n = b>>8, patch = b&255
    int n = b >> 8;
    int pb = b & 255;
    int w0 = (pb & 15) << 3, h0 = (pb >> 4) << 3;
    int w = w0 + (tid & 7), h = h0 + (tid >> 3);
    int oidx = (n << 14) + (h << 7) + w;
    float base = subsrc ? subsrc[oidx] : 0.0f;
    float sgn = subsrc ? -1.0f : 1.0f;

    const float* C = cst + n * CSTR;
    float r00=C[0], r01=C[1];
    float r10=C[4], r11=C[5];
    float r20=C[8], r21=C[9];

    float uc = (w0 + 3.5f - 63.5f) * RES_RATIO;
    float vc = (h0 + 3.5f - 63.5f) * RES_RATIO;
    const float du = 5.25f, dv = 5.25f;
    float cx = r00*uc + r01*vc + C[12];
    float cy = r10*uc + r11*vc + C[13];
    float cz = r20*uc + r21*vc + C[14];
    float hx = fabsf(r00)*du + fabsf(r01)*dv + C[18];
    float hy = fabsf(r10)*du + fabsf(r11)*dv + C[19];
    float hz = fabsf(r20)*du + fabsf(r21)*dv + C[20];
    int tx0 = (int)floorf(cx - hx);
    int ty0 = (int)floorf(cy - hy);
    int tz0 = (int)floorf(cz - hz);

    if (tx0 >= 128 || tx0 + TNX <= 0 || ty0 >= 128 || ty0 + TNY <= 0 ||
        tz0 >= 128 || tz0 + TNZ <= 0) {
        out[oidx] = base;
        return;
    }

    __shared__ float tile[TNZ * TNY * TNX];
    for (int i = tid; i < TNZ * TNY * TNX; i += 64) {
        int xx = i % TNX; int rem = i / TNX;
        int yy = rem % TNY; int zz = rem / TNY;
        int gx = tx0 + xx, gy = ty0 + yy, gz = tz0 + zz;
        bool ok = ((unsigned)gx < 128u) & ((unsigned)gy < 128u) & ((unsigned)gz < 128u);
        int off = ok ? ((gz << 14) + (gy << 7) + gx) : 0;
        float v = vol[off];
        tile[i] = ok ? v : 0.0f;
    }
    __syncthreads();

    float u = (w - 63.5f) * RES_RATIO;
    float v = (h - 63.5f) * RES_RATIO;
    float px = fmaf(r00, u, fmaf(r01, v, C[12])) - (float)tx0;
    float py = fmaf(r10, u, fmaf(r11, v, C[13])) - (float)ty0;
    float pz = fmaf(r20, u, fmaf(r21, v, C[14])) - (float)tz0;

    const float* O = C + 24;
    float acc = 0.0f;
    for (int k = 0; k < 27; ++k) {
        float sx = px + O[3*k+0];
        float sy = py + O[3*k+1];
        float sz = pz + O[3*k+2];
        int x0 = (int)sx, y0 = (int)sy, z0 = (int)sz;
        float fx = sx - (float)x0, fy = sy - (float)y0, fz = sz - (float)z0;
        const float* tp = tile + (z0 * TNY + y0) * TNX + x0;
        float c000 = tp[0],             c001 = tp[1];
        float c010 = tp[TNX],           c011 = tp[TNX+1];
        float c100 = tp[TNY*TNX],       c101 = tp[TNY*TNX+1];
        float c110 = tp[TNY*TNX+TNX],   c111 = tp[TNY*TNX+TNX+1];
        float c00 = fmaf(fx, c001 - c000, c000);
        float c01 = fmaf(fx, c011 - c010, c010);
        float c10 = fmaf(fx, c101 - c100, c100);
        float c11 = fmaf(fx, c111 - c110, c110);
        float c0  = fmaf(fy, c01 - c00, c00);
        float c1  = fmaf(fy, c11 - c10, c10);
        acc = fmaf(psf[k], fmaf(fz, c1 - c0, c0), acc);
    }
    out[oidx] = fmaf(sgn, acc, base);
}

// ---------------------------------------------------------------------------
// At, z-split scatter (arithmetic unchanged since R2; contributions bitwise-
// identical). PSF symmetry (pfx0==pfx2, pfy0==pfy2 bitwise: Gaussian, (+-1)^2
// computed identically on host) lets fx/fy selects collapse to 1 cndmask —
// selection among bitwise-equal values, exact.
// ~1.2M atomicAdds total; outvol must be pre-zeroed. No barriers.
// ---------------------------------------------------------------------------
#define ATS_CL(B_) fmaxf(1.0f - fabsf(B_), 0.0f)
#define ATS_PT(cAi, cBi, cCi, Xai, Yai, Zai, SEL, fyj, mvj, ACC) { \
    float sf_  = SEL(cAi, cBi, cCi); \
    float svf_ = sf_ * fyj; \
    float Bx_ = fmaf(r01, mvj, Xai); \
    float By_ = fmaf(r11, mvj, Yai); \
    float Bz_ = fmaf(r21, mvj, Zai); \
    float w0_ = ATS_CL(Bx_ - r02) * ATS_CL(By_ - r12) * ATS_CL(Bz_ - r22); \
    float w1_ = ATS_CL(Bx_) * ATS_CL(By_) * ATS_CL(Bz_); \
    float w2_ = ATS_CL(Bx_ + r02) * ATS_CL(By_ + r12) * ATS_CL(Bz_ + r22); \
    float t_  = fmaf(w0_, pfz0, fmaf(w1_, pfz1, w2_ * pfz2)); \
    ACC = fmaf(t_, svf_, ACC); }
#define ATS_ROW(SEL, fyj, mvj) \
    ATS_PT(cA0,cB0,cC0, Xa0,Ya0,Za0, SEL, fyj, mvj, acc0) \
    ATS_PT(cA1,cB1,cC1, Xa1,Ya1,Za1, SEL, fyj, mvj, acc1) \
    ATS_PT(cA2,cB2,cC2, Xa2,Ya2,Za2, SEL, fyj, mvj, acc0) \
    ATS_PT(cA3,cB3,cC3, Xa3,Ya3,Za3, SEL, fyj, mvj, acc1) \
    ATS_PT(cA4,cB4,cC4, Xa4,Ya4,Za4, SEL, fyj, mvj, acc0)
#define SEL_J0(a,b,c) (mj1 ? (b) : (a))
#define SEL_J1(a,b,c) (mj1 ? (a) : (b))
#define SEL_J2(a,b,c) (mj1 ? (b) : (mj2 ? (c) : (a)))
#define SEL_J3(a,b,c) (mj1 ? (c) : (b))
#define SEL_J4(a,b,c) (mj1 ? (b) : (c))

__global__ __launch_bounds__(256, 4) void at_scatter_kernel(
    const float* __restrict__ cst, const float* __restrict__ sl,
    float* __restrict__ outvol)
{
    int id = blockIdx.x * 256 + threadIdx.x;    // exact grid: NPIX*ZSL threads
    int x = id & 127, y = (id >> 7) & 127;
    int n = (id >> 14) & 15, zi = id >> 18;     // n, zi block-uniform
    const float* C = cst + n * CSTR;
    float r00=C[0], r01=C[1], r02=C[2];
    float r10=C[4], r11=C[5], r12=C[6];
    float r20=C[8], r21=C[9], r22=C[10];
    float tc2 = C[14];
    float C0=C[15], C1=C[16];

    float gx = (float)x - C[12];
    float gy = (float)y - C[13];

    // gpz(z) = az + r22*z ; active: |gpz| < lim. r22 > 0 always.
    float az = r02*gx + r12*gy + C[109];
    float lim = C[105];
    float inv22 = C[106];
    int z0 = (int)ceilf((-lim - az) * inv22);
    int z1v = (int)floorf(( lim - az) * inv22);
    z0 = max(z0, 0); z1v = min(z1v, 127);
    int z = z0 + zi;
    if (z > z1v) return;                        // no barriers: safe

    float ax = r00*gx + r10*gy + C[107];        // gpx = ax + r20*z
    float ay = r01*gx + r11*gy + C[108];        // gpy = ay + r21*z

    float fzv = (float)z;
    float gpx = fmaf(r20, fzv, ax);
    float gpy = fmaf(r21, fzv, ay);
    float gz  = fzv - tc2;
    int m2 = (int)floorf(2.0f*(gpx + 95.25f - C0)) + 601;
    int n2 = (int)floorf(2.0f*(gpy + 95.25f - C1)) + 601;
    int wb0 = m2 / 3;                           // biased by 200 (per-z anchor)
    int hb0 = n2 / 3;
    int ki0 = m2 - wb0 * 3;
    int kj0 = n2 - hb0 * 3;

    // 3x3 sval register block, OOB-masked (per-z anchor => ci,rj in 0..2)
    const float* slice_n = sl + (n << 14);
    float s[3][3];
    #pragma unroll
    for (int aa = 0; aa < 3; ++aa) {
        int hv = hb0 - 200 + aa;
        bool hok = ((unsigned)hv < 128u);
        #pragma unroll
        for (int cc = 0; cc < 3; ++cc) {
            int wv = wb0 - 200 + cc;
            bool ok = hok & ((unsigned)wv < 128u);
            int off = ok ? ((hv << 7) + wv) : 0;
            float vs = slice_n[off];
            s[aa][cc] = ok ? vs : 0.0f;
        }
    }

    const float* G = cst + NS * CSTR;
    float pfx0=G[0], pfx1=G[1];
    float pfy0=G[3], pfy1=G[4];
    float pfz0=G[6], pfz1=G[7], pfz2=G[8];

    int yx = (y << 7) + x;

    bool mi0 = (ki0 == 0), mi1 = (ki0 == 1), mi2 = (ki0 == 2);
    bool mj0 = (kj0 == 0), mj1 = (kj0 == 1), mj2 = (kj0 == 2);

    // fx values (period 3; pfx0==pfx2 bitwise -> single selects)
    float fxA = mi0 ? pfx1 : pfx0;
    float fxB = mi2 ? pfx1 : pfx0;
    float fxC = mi1 ? pfx1 : pfx0;

    float fyA = mj0 ? pfy1 : pfy0;
    float fyB = mj2 ? pfy1 : pfy0;
    float fyC = mj1 ? pfy1 : pfy0;

    // Column-selected s-values per i (R2 tables), premultiplied by fx.
    float cA0 = (mi1 ? s[0][1] : s[0][0]) * fxA;
    float cB0 = (mi1 ? s[1][1] : s[1][0]) * fxA;
    float cC0 = (mi1 ? s[2][1] : s[2][0]) * fxA;
    float cA1 = (mi1 ? s[0][0] : s[0][1]) * fxB;
    float cB1 = (mi1 ? s[1][0] : s[1][1]) * fxB;
    float cC1 = (mi1 ? s[2][0] : s[2][1]) * fxB;
    float cA2 = (mi1 ? s[0][1] : (mi2 ? s[0][2] : s[0][0])) * fxC;
    float cB2 = (mi1 ? s[1][1] : (mi2 ? s[1][2] : s[1][0])) * fxC;
    float cC2 = (mi1 ? s[2][1] : (mi2 ? s[2][2] : s[2][0])) * fxC;
    float cA3 = (mi1 ? s[0][2] : s[0][1]) * fxA;
    float cB3 = (mi1 ? s[1][2] : s[1][1]) * fxA;
    float cC3 = (mi1 ? s[2][2] : s[2][1]) * fxA;
    float cA4 = (mi1 ? s[0][1] : s[0][2]) * fxB;
    float cB4 = (mi1 ? s[1][1] : s[1][2]) * fxB;
    float cC4 = (mi1 ? s[2][1] : s[2][2]) * fxB;

    float mu0_ = 0.5f * (float)(m2 - 600) - 95.25f;
    float mu1_ = 0.5f * (float)(m2 - 599) - 95.25f;
    float mu2_ = 0.5f * (float)(m2 - 598) - 95.25f;
    float mu3_ = 0.5f * (float)(m2 - 597) - 95.25f;
    float mu4_ = 0.5f * (float)(m2 - 596) - 95.25f;
    float Xa0 = fmaf(r00, mu0_, -gx), Ya0 = fmaf(r10, mu0_, -gy), Za0 = fmaf(r20, mu0_, -gz);
    float Xa1 = fmaf(r00, mu1_, -gx), Ya1 = fmaf(r10, mu1_, -gy), Za1 = fmaf(r20, mu1_, -gz);
    float Xa2 = fmaf(r00, mu2_, -gx), Ya2 = fmaf(r10, mu2_, -gy), Za2 = fmaf(r20, mu2_, -gz);
    float Xa3 = fmaf(r00, mu3_, -gx), Ya3 = fmaf(r10, mu3_, -gy), Za3 = fmaf(r20, mu3_, -gz);
    float Xa4 = fmaf(r00, mu4_, -gx), Ya4 = fmaf(r10, mu4_, -gy), Za4 = fmaf(r20, mu4_, -gz);

    // Keep-alive: force materialization of all loop-invariant values.
    asm volatile("" ::
        "v"(cA0),"v"(cA1),"v"(cA2),"v"(cA3),"v"(cA4),
        "v"(cB0),"v"(cB1),"v"(cB2),"v"(cB3),"v"(cB4),
        "v"(cC0),"v"(cC1),"v"(cC2),"v"(cC3),"v"(cC4),
        "v"(Xa0),"v"(Xa1),"v"(Xa2),"v"(Xa3),"v"(Xa4),
        "v"(Ya0),"v"(Ya1),"v"(Ya2),"v"(Ya3),"v"(Ya4),
        "v"(Za0),"v"(Za1),"v"(Za2),"v"(Za3),"v"(Za4),
        "v"(fyA),"v"(fyB),"v"(fyC));

    float mv0_ = 0.5f * (float)(n2 - 600) - 95.25f;
    float mv1_ = 0.5f * (float)(n2 - 599) - 95.25f;
    float mv2_ = 0.5f * (float)(n2 - 598) - 95.25f;
    float mv3_ = 0.5f * (float)(n2 - 597) - 95.25f;
    float mv4_ = 0.5f * (float)(n2 - 596) - 95.25f;

    float acc0 = 0.0f, acc1 = 0.0f;
    ATS_ROW(SEL_J0, fyA, mv0_)
    ATS_ROW(SEL_J1, fyB, mv1_)
    ATS_ROW(SEL_J2, fyC, mv2_)
    ATS_ROW(SEL_J3, fyA, mv3_)
    ATS_ROW(SEL_J4, fyB, mv4_)

    atomicAdd(&outvol[(z << 14) + yx], acc0 + acc1);
}

// p = r; Ap = 0; rr0 += r^2   [slab-skipped, block-uniform]
__global__ __launch_bounds__(256) void initpr_kernel(
    const float* __restrict__ r, float* __restrict__ p, float* __restrict__ Ap,
    double* __restrict__ rr_slots, const int* __restrict__ zb)
{
    int z = blockIdx.x >> 6;
    if (z < zb[0] || z > zb[1]) return;
    int i = blockIdx.x * 256 + threadIdx.x;
    float rv = r[i];
    p[i] = rv;
    Ap[i] = 0.0f;
    block_reduce_spread((double)rv * (double)rv, rr_slots);
}

// {pAp, rAp, ApAp} over the slab
__global__ __launch_bounds__(256) void dots_kernel(
    const float* __restrict__ Ap, const float* __restrict__ p,
    const float* __restrict__ r,
    double* __restrict__ s_pap, double* __restrict__ s_rap,
    double* __restrict__ s_apap, const int* __restrict__ zb)
{
    int z = blockIdx.x >> 6;
    if (z < zb[0] || z > zb[1]) return;
    int i = blockIdx.x * 256 + threadIdx.x;
    double a = (double)Ap[i];
    block_reduce3(a * (double)p[i], a * (double)r[i], a * a,
                  s_pap, s_rap, s_apap);
}

// ---------------------------------------------------------------------------
// Merged CG update: alpha = rr_old/pAp; rr_new = rr_old - 2a*rAp + a^2*ApAp;
// beta = rr_new/rr_old; x += a p; r -= a Ap; p = r + beta p; Ap = 0 (for the
// next iteration's scatter).
// ---------------------------------------------------------------------------
__global__ __launch_bounds__(256) void update_kernel(
    float* __restrict__ x, float* __restrict__ r, float* __restrict__ p,
    float* __restrict__ Ap,
    const double* __restrict__ rr_src, int rr_is_slots,
    const double* __restrict__ paps, const double* __restrict__ raps,
    const double* __restrict__ apaps, double* __restrict__ rr_out,
    const int* __restrict__ zb, float* __restrict__ outp)
{
    __shared__ float sh_ab[2];
    int tid = threadIdx.x;
    if (tid < 64) {
        double v0 = rr_is_slots ? rr_src[tid * 32] : 0.0;
        double v1 = paps[tid * 32];
        double v2 = raps[tid * 32];
        double v3 = apaps[tid * 32];
        #pragma unroll
        for (int off = 32; off > 0; off >>= 1) {
            v0 += __shfl_down(v0, off, 64);
            v1 += __shfl_down(v1, off, 64);
            v2 += __shfl_down(v2, off, 64);
            v3 += __shfl_down(v3, off, 64);
        }
        if (tid == 0) {
            double rr_old = rr_is_slots ? v0 : rr_src[0];
            double alpha = rr_old / v1;
            double rr_new = rr_old - 2.0 * alpha * v2 + alpha * alpha * v3;
            if (blockIdx.x == 0) rr_out[0] = rr_new;
            sh_ab[0] = (float)alpha;
            sh_ab[1] = (float)(rr_new / rr_old);
        }
    }
    __syncthreads();
    float af = sh_ab[0], bf = sh_ab[1];

    int z = blockIdx.x >> 6;
    int i = blockIdx.x * 256 + tid;
    bool inslab = (z >= zb[0]) & (z <= zb[1]);
    if (!inslab) {
        if (outp) outp[i] = fmaxf(x[i], 0.0f);
        return;
    }
    float xv = fmaf(af, p[i], x[i]);
    x[i] = xv;
    float apv = Ap[i];
    Ap[i] = 0.0f;
    float rvv = fmaf(-af, apv, r[i]);
    r[i] = rvv;
    p[i] = fmaf(bf, p[i], rvv);
    if (outp) outp[i] = fmaxf(xv, 0.0f);
}

extern "C" void kernel_launch(void* const* d_in, const int* in_sizes, int n_in,
                              void* d_out, int out_size, void* d_ws, size_t ws_size,
                              hipStream_t stream) {
    const float* theta  = (const float*)d_in[0];  // [16,3,4]
    const float* slices = (const float*)d_in[1];  // [16,1,128,128]
    const float* volume = (const float*)d_in[2];  // [1,1,128,128,128]
    const float* psf    = (const float*)d_in[3];  // [3,3,3]
    float* out = (float*)d_out;

    char* ws = (char*)d_ws;
    float* x  = (float*)ws;
    float* r  = x  + VOX;     // r and p contiguous (single memset covers both)
    float* p  = r  + VOX;
    float* Ap = p  + VOX;
    float* sl = Ap + VOX;
    double* sc = (double*)(sl + NPIX);
    double* rrs0  = sc;             // 64 slots * stride 32 doubles (16 KB)
    double* paps  = sc + 2048;
    double* raps  = sc + 4096;
    double* apaps = sc + 6144;
    double* rr_sc = sc + 8192;      // rr chain scalars [0..10]
    float* cst = (float*)(sc + 8208);        // 16*128 floats + 9 globals
    int* zb = (int*)(cst + NS * CSTR + 16);  // [zlo, zhi]

    const int gapix = NPIX / 64;        // 4096 (a_kernel: 64-thread blocks)
    const int gvox = VOX / 256;         // 8192
    const int gsc  = NPIX * ZSL / 256;  // 5120 (at_scatter: thread per (x,y,n,zi))

    prep_kernel<<<1, 512, 0, stream>>>(theta, psf, cst, zb);

    // x = volume; r = p = 0 (exact zeros; r is at_scatter's first target)
    hipMemcpyAsync(x, volume, VOX * sizeof(float), hipMemcpyDeviceToDevice, stream);
    hipMemsetAsync(r, 0, 2 * VOX * sizeof(float), stream);

    // sl = slices - A(x0)   (a_kernel zeroes rrs0)
    a_kernel<<<gapix, 64, 0, stream>>>(cst, x, psf, sl, slices, rrs0, nullptr, nullptr);
    // r += At(sl) = b - AtA x0  (scatter into zeroed r)
    at_scatter_kernel<<<gsc, 256, 0, stream>>>(cst, sl, r);
    // p = r; Ap = 0; rr0 = dot(r,r)
    initpr_kernel<<<gvox, 256, 0, stream>>>(r, p, Ap, rrs0, zb);

    for (int it = 0; it < 10; ++it) {
        // a_kernel zeroes the three dot-slot arrays (consumers done)
        a_kernel<<<gapix, 64, 0, stream>>>(cst, p, psf, sl, nullptr, paps, raps, apaps);
        // Ap += At(A p)   (Ap zeroed by initpr / previous update)
        at_scatter_kernel<<<gsc, 256, 0, stream>>>(cst, sl, Ap);
        // {pAp, rAp, ApAp}
        dots_kernel<<<gvox, 256, 0, stream>>>(Ap, p, r, paps, raps, apaps, zb);

        const double* rr_src = (it == 0) ? rrs0 : &rr_sc[it];
        update_kernel<<<gvox, 256, 0, stream>>>(
            x, r, p, Ap, rr_src, (it == 0) ? 1 : 0,
            paps, raps, apaps, &rr_sc[it + 1], zb, (it == 9) ? out : nullptr);
    }
}